// Round 22
// baseline (472.580 us; speedup 1.0000x reference)
//
#include <hip/hip_runtime.h>
#include <hip/hip_bf16.h>

typedef __attribute__((ext_vector_type(8))) short bf16x8;
typedef __attribute__((ext_vector_type(4))) float f32x4;
typedef __attribute__((ext_vector_type(8))) unsigned short u16x8;

// ---------- helpers ----------
__device__ inline unsigned short f2bf(float f) {
  unsigned u = __builtin_bit_cast(unsigned, f);
  u += 0x7FFFu + ((u >> 16) & 1u);   // round-to-nearest-even
  return (unsigned short)(u >> 16);
}
__device__ inline float b2f(unsigned short h) {
  unsigned u = ((unsigned)h) << 16;
  return __builtin_bit_cast(float, u);
}

typedef const __attribute__((address_space(1))) void* gas_ptr;
typedef __attribute__((address_space(3))) void* las_ptr;
__device__ inline void load_lds16(const void* g, void* l) {
  __builtin_amdgcn_global_load_lds((gas_ptr)g, (las_ptr)l, 16, 0, 0);
}

// ---------- f32 -> bf16 conversion (vectorized x4) ----------
__global__ __launch_bounds__(256) void cvt_f32_bf16(const float* __restrict__ src,
                                                    unsigned short* __restrict__ dst,
                                                    int n4) {
  int i = blockIdx.x * 256 + threadIdx.x;
  if (i >= n4) return;
  float4 v = ((const float4*)src)[i];
  ushort4 o;
  o.x = f2bf(v.x); o.y = f2bf(v.y); o.z = f2bf(v.z); o.w = f2bf(v.w);
  ((ushort4*)dst)[i] = o;
}

// ---------- staging: XOR-swizzled source, linear LDS dest ----------
template <int NLOADS>
__device__ inline void stage_tile(const unsigned short* __restrict__ g, int ld,
                                  size_t grow0, int kcol0, char* ldsdst, int tid) {
#pragma unroll
  for (int i = 0; i < NLOADS; ++i) {
    int c = tid + i * 512;
    int r = c >> 3;
    int k = (c & 7) ^ (r & 7);
    load_lds16(g + (grow0 + r) * ld + kcol0 + k * 8, ldsdst + c * 16);
  }
}

// 2D XCD chunking (round-10 verified: FETCH -50%)
__device__ inline void xcd_decode(int orig, int nTM, int nTN, int& bm, int& bn) {
  int x = orig & 7, i = orig >> 3;
  int xr = x >> 1, xc = x & 1;
  int bmch = nTM >> 2, bnch = nTN >> 1;
  bm = xr * bmch + i / bnch;
  bn = xc * bnch + i % bnch;
}

// ---------- 128x256-tile SINGLE-REGION pipelined GEMM (QKV) + fused RoPE ----------
template <int Kc, int Nc, int Mc, bool OUT_F32, bool FUSE_ROPE>
__global__ __launch_bounds__(512, 1) void gemmP(const unsigned short* __restrict__ A,
                                                const unsigned short* __restrict__ B,
                                                void* __restrict__ Cv,
                                                const int* __restrict__ positions) {
  __shared__ __attribute__((aligned(16))) char lds[147456];   // 3 x 48 KiB
  const int tid = threadIdx.x;
  const int wave = tid >> 6, lane = tid & 63;
  const int l15 = lane & 15, l4 = lane >> 4;
  const int wr = wave >> 2, wc = wave & 3;          // 2 x 4 wave grid, 64x64 each
  const int hc = wc >> 1, sb = (wc & 1) << 5;       // head-within-tile, strip base
  int bm, bn;
  xcd_decode(blockIdx.x, Mc >> 7, Nc >> 8, bm, bn);
  const size_t rowA0 = (size_t)bm << 7, rowB0 = (size_t)bn << 8;
  const int nt = Kc >> 6;

  stage_tile<2>(A, Kc, rowA0, 0,  lds + 0,             tid);
  stage_tile<4>(B, Kc, rowB0, 0,  lds + 16384,         tid);
  stage_tile<2>(A, Kc, rowA0, 64, lds + 49152,         tid);
  stage_tile<4>(B, Kc, rowB0, 64, lds + 49152 + 16384, tid);
  asm volatile("s_waitcnt vmcnt(6)" ::: "memory");   // tile0 landed
  __builtin_amdgcn_s_barrier();

  f32x4 acc[4][4] = {};

#pragma unroll 3
  for (int t = 0; t < nt; ++t) {
    const char* bufA = lds + (t % 3) * 49152;
    const char* bufB = bufA + 16384;
    char* sbuf = lds + ((t + 2) % 3) * 49152;       // last read at t-1: dead
    const int kc2 = (t + 2) << 6;

    if (t < nt - 2) {
      stage_tile<4>(B, Kc, rowB0, kc2, sbuf + 16384, tid);
      stage_tile<2>(A, Kc, rowA0, kc2, sbuf, tid);
    }

    bf16x8 af[4][2], bf[4][2];
#pragma unroll
    for (int m = 0; m < 4; ++m) {
      int row = wr * 64 + m * 16 + l15;
#pragma unroll
      for (int kk = 0; kk < 2; ++kk)
        af[m][kk] = *(const bf16x8*)(bufA + (row << 7) + (((kk * 4 + l4) ^ (row & 7)) << 4));
    }
#pragma unroll
    for (int n = 0; n < 4; ++n) {
      int row = hc * 128 + sb + (n & 1) * 16 + ((n >> 1) << 6) + l15;
#pragma unroll
      for (int kk = 0; kk < 2; ++kk)
        bf[n][kk] = *(const bf16x8*)(bufB + (row << 7) + (((kk * 4 + l4) ^ (row & 7)) << 4));
    }

#pragma unroll
    for (int m = 0; m < 4; ++m)
#pragma unroll
      for (int n = 0; n < 4; ++n)
#pragma unroll
        for (int kk = 0; kk < 2; ++kk)
          acc[m][n] = __builtin_amdgcn_mfma_f32_16x16x32_bf16(af[m][kk], bf[n][kk], acc[m][n], 0, 0, 0);

    if (t <= nt - 3) { asm volatile("s_waitcnt vmcnt(6)" ::: "memory"); }
    else             { asm volatile("s_waitcnt vmcnt(0)" ::: "memory"); }
    asm volatile("" ::: "memory");
    __builtin_amdgcn_s_barrier();
    asm volatile("" ::: "memory");
  }

  // ---- fused RoPE (q: bn 0..15, k: bn 16..19; v tiles skip) ----
  if (FUSE_ROPE && bn < 20) {
    float invf[2];
#pragma unroll
    for (int n = 0; n < 2; ++n) {
      int d = sb + n * 16 + l15;                 // head-local dim in [0,64)
      invf[n] = exp2f(-(float)d * 0.20762050593046007f);   // 10000^(-d/64)
    }
#pragma unroll
    for (int m = 0; m < 4; ++m)
#pragma unroll
      for (int r = 0; r < 4; ++r) {
        int row = (int)rowA0 + wr * 64 + m * 16 + l4 * 4 + r;
        float pos = (float)positions[row];
#pragma unroll
        for (int n = 0; n < 2; ++n) {
          float s, c;
          __sincosf(pos * invf[n], &s, &c);      // HW v_sin/v_cos path
          float x1 = acc[m][n][r], x2 = acc[m][n + 2][r];
          acc[m][n][r]     = x1 * c - x2 * s;
          acc[m][n + 2][r] = x2 * c + x1 * s;
        }
      }
  }

  // ---- epilogue (paired-strip col mapping) ----
#pragma unroll
  for (int m = 0; m < 4; ++m)
#pragma unroll
    for (int n = 0; n < 4; ++n)
#pragma unroll
      for (int r = 0; r < 4; ++r) {
        size_t row = rowA0 + wr * 64 + m * 16 + l4 * 4 + r;
        size_t col = rowB0 + hc * 128 + sb + (n & 1) * 16 + ((n >> 1) << 6) + l15;
        float v = acc[m][n][r];
        if (OUT_F32) ((float*)Cv)[row * Nc + col] = v;
        else         ((unsigned short*)Cv)[row * Nc + col] = f2bf(v);
      }
}

// ---------- 256x256-tile SINGLE-REGION GEMM (O-proj), 64x128 per wave ----------
template <int Kc, int Nc, int Mc, bool OUT_F32>
__global__ __launch_bounds__(512, 1) void gemmO(const unsigned short* __restrict__ A,
                                                const unsigned short* __restrict__ B,
                                                void* __restrict__ Cv) {
  __shared__ __attribute__((aligned(16))) char lds[131072];   // 2 x 64 KiB
  const int tid = threadIdx.x;
  const int wave = tid >> 6, lane = tid & 63;
  const int l15 = lane & 15, l4 = lane >> 4;
  const int wr = wave >> 1, wc = wave & 1;          // 4M x 2N grid, 64x128 each
  int bm, bn;
  xcd_decode(blockIdx.x, Mc >> 8, Nc >> 8, bm, bn);
  const size_t rowA0 = (size_t)bm << 8, rowB0 = (size_t)bn << 8;
  const int nt = Kc >> 6;

  stage_tile<4>(A, Kc, rowA0, 0, lds + 0,     tid);
  stage_tile<4>(B, Kc, rowB0, 0, lds + 32768, tid);
  asm volatile("s_waitcnt vmcnt(0)" ::: "memory");
  __builtin_amdgcn_s_barrier();

  f32x4 acc[4][8] = {};

#pragma unroll 2
  for (int t = 0; t < nt; ++t) {
    const char* cbuf = lds + (t & 1) * 65536;
    char* obuf = lds + ((t + 1) & 1) * 65536;
    const char* bufA = cbuf;
    const char* bufB = cbuf + 32768;

    if (t < nt - 1) {
      stage_tile<4>(A, Kc, rowA0, (t + 1) << 6, obuf,         tid);
      stage_tile<4>(B, Kc, rowB0, (t + 1) << 6, obuf + 32768, tid);
    }

    bf16x8 af[4][2], bf[4][2];
#pragma unroll
    for (int m = 0; m < 4; ++m) {
      int row = wr * 64 + m * 16 + l15;
#pragma unroll
      for (int kk = 0; kk < 2; ++kk)
        af[m][kk] = *(const bf16x8*)(bufA + (row << 7) + (((kk * 4 + l4) ^ (row & 7)) << 4));
    }
#pragma unroll
    for (int n = 0; n < 4; ++n) {
      int row = wc * 128 + n * 16 + l15;
#pragma unroll
      for (int kk = 0; kk < 2; ++kk)
        bf[n][kk] = *(const bf16x8*)(bufB + (row << 7) + (((kk * 4 + l4) ^ (row & 7)) << 4));
    }
#pragma unroll
    for (int m = 0; m < 4; ++m)
#pragma unroll
      for (int n = 0; n < 4; ++n)
#pragma unroll
        for (int kk = 0; kk < 2; ++kk)
          acc[m][n] = __builtin_amdgcn_mfma_f32_16x16x32_bf16(af[m][kk], bf[n][kk], acc[m][n], 0, 0, 0);
#pragma unroll
    for (int n = 0; n < 4; ++n) {
      int row = wc * 128 + (n + 4) * 16 + l15;
#pragma unroll
      for (int kk = 0; kk < 2; ++kk)
        bf[n][kk] = *(const bf16x8*)(bufB + (row << 7) + (((kk * 4 + l4) ^ (row & 7)) << 4));
    }
#pragma unroll
    for (int m = 0; m < 4; ++m)
#pragma unroll
      for (int n = 0; n < 4; ++n)
#pragma unroll
        for (int kk = 0; kk < 2; ++kk)
          acc[m][n + 4] = __builtin_amdgcn_mfma_f32_16x16x32_bf16(af[m][kk], bf[n][kk], acc[m][n + 4], 0, 0, 0);

    asm volatile("s_waitcnt vmcnt(0)" ::: "memory");
    asm volatile("" ::: "memory");
    __builtin_amdgcn_s_barrier();
    asm volatile("" ::: "memory");
  }

#pragma unroll
  for (int m = 0; m < 4; ++m)
#pragma unroll
    for (int n = 0; n < 8; ++n)
#pragma unroll
      for (int r = 0; r < 4; ++r) {
        size_t row = rowA0 + wr * 64 + m * 16 + l4 * 4 + r;
        size_t col = rowB0 + wc * 128 + n * 16 + l15;
        float v = acc[m][n][r];
        if (OUT_F32) ((float*)Cv)[row * Nc + col] = v;
        else         ((unsigned short*)Cv)[row * Nc + col] = f2bf(v);
      }
}

// ---------- flash attention (R17 proven form + T5 setprio on MFMA clusters) ----------
__global__ __launch_bounds__(256, 4) void attn_kernel(const unsigned short* __restrict__ qkv,
                                                      unsigned short* __restrict__ ao) {
  int orig = blockIdx.x;
  int wgid = (orig & 7) * 128 + (orig >> 3);       // XCD-chunked swizzle (1024 % 8 == 0)
  int pair = wgid & 7;
  int hq = (wgid >> 3) & 31;
  int b  = wgid >> 8;
  int hk = hq >> 2;
  int tid = threadIdx.x, wave = tid >> 6, lane = tid & 63;
  int l15 = lane & 15, l4 = lane >> 4;

  __shared__ __attribute__((aligned(16))) char ldsA[16384];                 // Ks / Ps union
  __shared__ __attribute__((aligned(16))) unsigned short Vt[128][72];       // 18 KB
  unsigned short (*Ks)[128]    = (unsigned short (*)[128])ldsA;             // [64][128]
  unsigned short (*Ps)[16][72] = (unsigned short (*)[16][72])ldsA;          // [4][16][72]

  const float scale = 0.08838834764831845f;  // 1/sqrt(128)

#pragma unroll 1
  for (int iq = 0; iq < 2; ++iq) {
    const int qa = iq ? (15 - pair) : pair;        // work = qa+1 tiles; pair total = 17
    const size_t qrow0 = (size_t)(b * 1024 + qa * 64 + wave * 16);

    bf16x8 qf[4];
    {
      const unsigned short* qp = qkv + (qrow0 + l15) * 6144 + ((size_t)hq << 7) + l4 * 8;
#pragma unroll
      for (int kc = 0; kc < 4; ++kc) qf[kc] = *(const bf16x8*)(qp + kc * 32);
    }

    float m_i[4], l_i[4];
    f32x4 oacc[8];
#pragma unroll
    for (int r = 0; r < 4; ++r) { m_i[r] = -1e30f; l_i[r] = 0.0f; }
#pragma unroll
    for (int d = 0; d < 8; ++d) oacc[d] = f32x4{0.f, 0.f, 0.f, 0.f};

#pragma unroll 1
    for (int kt = 0; kt <= qa; ++kt) {
      __syncthreads();

      const unsigned short* kbase = qkv + (size_t)(b * 1024 + kt * 64) * 6144 + 4096 + ((size_t)hk << 7);
#pragma unroll
      for (int j = 0; j < 4; ++j) {
        int c = (j * 4 + wave) * 64 + lane;
        int r = c >> 4;
        int cc = (c & 15) ^ (r & 7);
        load_lds16(kbase + (size_t)r * 6144 + cc * 8, ldsA + c * 16);
      }
      {
        const unsigned short* vp = qkv + (size_t)(b * 1024 + kt * 64 + lane) * 6144 + 5120 + ((size_t)hk << 7) + wave * 32;
        u16x8 va0 = *(const u16x8*)(vp);
        u16x8 va1 = *(const u16x8*)(vp + 8);
        u16x8 va2 = *(const u16x8*)(vp + 16);
        u16x8 va3 = *(const u16x8*)(vp + 24);
        int d0 = wave * 32;
#pragma unroll
        for (int c = 0; c < 8; ++c) Vt[d0 + c][lane]      = va0[c];
#pragma unroll
        for (int c = 0; c < 8; ++c) Vt[d0 + 8 + c][lane]  = va1[c];
#pragma unroll
        for (int c = 0; c < 8; ++c) Vt[d0 + 16 + c][lane] = va2[c];
#pragma unroll
        for (int c = 0; c < 8; ++c) Vt[d0 + 24 + c][lane] = va3[c];
      }
      __syncthreads();

      float pbuf[4][4];
      float tmax[4] = {-1e30f, -1e30f, -1e30f, -1e30f};
#pragma unroll
      for (int nt = 0; nt < 4; ++nt) {
        f32x4 sacc = {0.f, 0.f, 0.f, 0.f};
        int row = nt * 16 + l15;
        __builtin_amdgcn_s_setprio(1);
#pragma unroll
        for (int kc = 0; kc < 4; ++kc) {
          const unsigned short* kp = &Ks[0][0] + row * 128 + (((kc * 4 + l4) ^ (row & 7)) * 8);
          bf16x8 kf = *(const bf16x8*)kp;
          sacc = __builtin_amdgcn_mfma_f32_16x16x32_bf16(qf[kc], kf, sacc, 0, 0, 0);
        }
        __builtin_amdgcn_s_setprio(0);
#pragma unroll
        for (int r = 0; r < 4; ++r) {
          float s = sacc[r] * scale;
          if (kt == qa) {
            int kcol = nt * 16 + l15;
            int qrow = wave * 16 + l4 * 4 + r;
            if (kcol > qrow) s = -1e30f;
          }
          pbuf[nt][r] = s;
          tmax[r] = fmaxf(tmax[r], s);
        }
      }
      __syncthreads();

#pragma unroll
      for (int r = 0; r < 4; ++r) {
        float v = tmax[r];
        v = fmaxf(v, __shfl_xor(v, 1));
        v = fmaxf(v, __shfl_xor(v, 2));
        v = fmaxf(v, __shfl_xor(v, 4));
        v = fmaxf(v, __shfl_xor(v, 8));
        tmax[r] = v;
      }
      float rescale[4];
#pragma unroll
      for (int r = 0; r < 4; ++r) {
        float mn = fmaxf(m_i[r], tmax[r]);
        rescale[r] = __expf(m_i[r] - mn);
        m_i[r] = mn;
      }
      float psum[4] = {0.f, 0.f, 0.f, 0.f};
#pragma unroll
      for (int nt = 0; nt < 4; ++nt)
#pragma unroll
        for (int r = 0; r < 4; ++r) {
          float p = __expf(pbuf[nt][r] - m_i[r]);
          pbuf[nt][r] = p;
          psum[r] += p;
        }
#pragma unroll
      for (int r = 0; r < 4; ++r) {
        float v = psum[r];
        v += __shfl_xor(v, 1);
        v += __shfl_xor(v, 2);
        v += __shfl_xor(v, 4);
        v += __shfl_xor(v, 8);
        l_i[r] = l_i[r] * rescale[r] + v;
      }
#pragma unroll
      for (int d = 0; d < 8; ++d)
#pragma unroll
        for (int r = 0; r < 4; ++r) oacc[d][r] *= rescale[r];

#pragma unroll
      for (int nt = 0; nt < 4; ++nt)
#pragma unroll
        for (int r = 0; r < 4; ++r)
          Ps[wave][l4 * 4 + r][nt * 16 + l15] = f2bf(pbuf[nt][r]);

#pragma unroll
      for (int h = 0; h < 2; ++h) {
        bf16x8 pa = *(const bf16x8*)&Ps[wave][l15][h * 32 + l4 * 8];
        __builtin_amdgcn_s_setprio(1);
#pragma unroll
        for (int d = 0; d < 8; ++d) {
          bf16x8 vf = *(const bf16x8*)&Vt[d * 16 + l15][h * 32 + l4 * 8];
          oacc[d] = __builtin_amdgcn_mfma_f32_16x16x32_bf16(pa, vf, oacc[d], 0, 0, 0);
        }
        __builtin_amdgcn_s_setprio(0);
      }
    }

#pragma unroll
    for (int d = 0; d < 8; ++d)
#pragma unroll
      for (int r = 0; r < 4; ++r) {
        size_t row = qrow0 + l4 * 4 + r;
        size_t col = ((size_t)hq << 7) + d * 16 + l15;
        ao[row * 4096 + col] = f2bf(oacc[d][r] / l_i[r]);
      }
  }
}

// ---------- launch ----------
extern "C" void kernel_launch(void* const* d_in, const int* in_sizes, int n_in,
                              void* d_out, int out_size, void* d_ws, size_t ws_size,
                              hipStream_t stream) {
  const float* hidden    = (const float*)d_in[0];
  const int*   positions = (const int*)d_in[1];
  const float* q_w       = (const float*)d_in[2];
  const float* k_w       = (const float*)d_in[3];
  const float* v_w       = (const float*)d_in[4];
  const float* o_w       = (const float*)d_in[5];
  float* out = (float*)d_out;

  char* ws = (char*)d_ws;
  unsigned short* hidB  = (unsigned short*)(ws);                 // 32 MB  [4096,4096]
  unsigned short* wqkvB = (unsigned short*)(ws + 33554432);      // 48 MB  [6144,4096]
  unsigned short* woB   = (unsigned short*)(ws + 83886080);      // 32 MB  [4096,4096]
  unsigned short* qkvB  = (unsigned short*)(ws + 117440512);     // 48 MB  [4096,6144]
  unsigned short* aoB   = (unsigned short*)(ws + 167772160);     // 32 MB  [4096,4096]

  // f32 -> bf16
  cvt_f32_bf16<<<16384, 256, 0, stream>>>(hidden, hidB, 4194304);
  cvt_f32_bf16<<<16384, 256, 0, stream>>>(q_w, wqkvB, 4194304);
  cvt_f32_bf16<<<4096, 256, 0, stream>>>(k_w, wqkvB + 16777216, 1048576);
  cvt_f32_bf16<<<4096, 256, 0, stream>>>(v_w, wqkvB + 20971520, 1048576);
  cvt_f32_bf16<<<16384, 256, 0, stream>>>(o_w, woB, 4194304);

  // fused QKV projection + RoPE: [4096,6144] = hid @ wqkv^T (768 tiles, 3 exact waves)
  gemmP<4096, 6144, 4096, false, true><<<768, 512, 0, stream>>>(hidB, wqkvB, (void*)qkvB, positions);

  // causal GQA flash attention (QBLK=64 proven form + setprio)
  attn_kernel<<<1024, 256, 0, stream>>>(qkvB, aoB);

  // output projection: [4096,4096] = ao @ o_w^T (256 tiles, 1 exact wave, f32 out)
  gemmO<4096, 4096, 4096, true><<<256, 512, 0, stream>>>(aoB, woB, (void*)out);
}

// Round 24
// 459.999 us; speedup vs baseline: 1.0274x; 1.0274x over previous
//
#include <hip/hip_runtime.h>
#include <hip/hip_bf16.h>

typedef __attribute__((ext_vector_type(8))) short bf16x8;
typedef __attribute__((ext_vector_type(4))) float f32x4;
typedef __attribute__((ext_vector_type(8))) unsigned short u16x8;

// ---------- helpers ----------
__device__ inline unsigned short f2bf(float f) {
  unsigned u = __builtin_bit_cast(unsigned, f);
  u += 0x7FFFu + ((u >> 16) & 1u);   // round-to-nearest-even
  return (unsigned short)(u >> 16);
}
__device__ inline float b2f(unsigned short h) {
  unsigned u = ((unsigned)h) << 16;
  return __builtin_bit_cast(float, u);
}

typedef const __attribute__((address_space(1))) void* gas_ptr;
typedef __attribute__((address_space(3))) void* las_ptr;
__device__ inline void load_lds16(const void* g, void* l) {
  __builtin_amdgcn_global_load_lds((gas_ptr)g, (las_ptr)l, 16, 0, 0);
}

// ---------- merged f32 -> bf16 conversion (all 5 tensors, one dispatch) ----------
__global__ __launch_bounds__(256) void cvt_all(const float* __restrict__ hidden,
                                               const float* __restrict__ q_w,
                                               const float* __restrict__ k_w,
                                               const float* __restrict__ v_w,
                                               const float* __restrict__ o_w,
                                               unsigned short* __restrict__ hidB,
                                               unsigned short* __restrict__ wqkvB,
                                               unsigned short* __restrict__ woB) {
  long gi = (long)blockIdx.x * 256 + threadIdx.x;   // float4 index
  const float* src;
  unsigned short* dst;
  long off;
  if (gi < 4194304L)        { src = hidden; dst = hidB;             off = gi; }
  else if (gi < 8388608L)   { src = q_w;    dst = wqkvB;            off = gi - 4194304L; }
  else if (gi < 9437184L)   { src = k_w;    dst = wqkvB + 16777216; off = gi - 8388608L; }
  else if (gi < 10485760L)  { src = v_w;    dst = wqkvB + 20971520; off = gi - 9437184L; }
  else                      { src = o_w;    dst = woB;              off = gi - 10485760L; }
  float4 v = ((const float4*)src)[off];
  ushort4 o;
  o.x = f2bf(v.x); o.y = f2bf(v.y); o.z = f2bf(v.z); o.w = f2bf(v.w);
  ((ushort4*)dst)[off] = o;
}

// ---------- staging: XOR-swizzled source, linear LDS dest ----------
template <int NLOADS>
__device__ inline void stage_tile(const unsigned short* __restrict__ g, int ld,
                                  size_t grow0, int kcol0, char* ldsdst, int tid) {
#pragma unroll
  for (int i = 0; i < NLOADS; ++i) {
    int c = tid + i * 512;
    int r = c >> 3;
    int k = (c & 7) ^ (r & 7);
    load_lds16(g + (grow0 + r) * ld + kcol0 + k * 8, ldsdst + c * 16);
  }
}

// 2D XCD chunking (round-10 verified: FETCH -50%)
__device__ inline void xcd_decode(int orig, int nTM, int nTN, int& bm, int& bn) {
  int x = orig & 7, i = orig >> 3;
  int xr = x >> 1, xc = x & 1;
  int bmch = nTM >> 2, bnch = nTN >> 1;
  bm = xr * bmch + i / bnch;
  bn = xc * bnch + i % bnch;
}

// ---------- 128x256-tile SINGLE-REGION pipelined GEMM (QKV) + fused RoPE ----------
template <int Kc, int Nc, int Mc, bool OUT_F32, bool FUSE_ROPE>
__global__ __launch_bounds__(512, 1) void gemmP(const unsigned short* __restrict__ A,
                                                const unsigned short* __restrict__ B,
                                                void* __restrict__ Cv,
                                                const int* __restrict__ positions) {
  __shared__ __attribute__((aligned(16))) char lds[147456];   // 3 x 48 KiB
  const int tid = threadIdx.x;
  const int wave = tid >> 6, lane = tid & 63;
  const int l15 = lane & 15, l4 = lane >> 4;
  const int wr = wave >> 2, wc = wave & 3;          // 2 x 4 wave grid, 64x64 each
  const int hc = wc >> 1, sb = (wc & 1) << 5;       // head-within-tile, strip base
  int bm, bn;
  xcd_decode(blockIdx.x, Mc >> 7, Nc >> 8, bm, bn);
  const size_t rowA0 = (size_t)bm << 7, rowB0 = (size_t)bn << 8;
  const int nt = Kc >> 6;

  stage_tile<2>(A, Kc, rowA0, 0,  lds + 0,             tid);
  stage_tile<4>(B, Kc, rowB0, 0,  lds + 16384,         tid);
  stage_tile<2>(A, Kc, rowA0, 64, lds + 49152,         tid);
  stage_tile<4>(B, Kc, rowB0, 64, lds + 49152 + 16384, tid);
  asm volatile("s_waitcnt vmcnt(6)" ::: "memory");   // tile0 landed
  __builtin_amdgcn_s_barrier();

  f32x4 acc[4][4] = {};

#pragma unroll 3
  for (int t = 0; t < nt; ++t) {
    const char* bufA = lds + (t % 3) * 49152;
    const char* bufB = bufA + 16384;
    char* sbuf = lds + ((t + 2) % 3) * 49152;       // last read at t-1: dead
    const int kc2 = (t + 2) << 6;

    if (t < nt - 2) {
      stage_tile<4>(B, Kc, rowB0, kc2, sbuf + 16384, tid);
      stage_tile<2>(A, Kc, rowA0, kc2, sbuf, tid);
    }

    bf16x8 af[4][2], bf[4][2];
#pragma unroll
    for (int m = 0; m < 4; ++m) {
      int row = wr * 64 + m * 16 + l15;
#pragma unroll
      for (int kk = 0; kk < 2; ++kk)
        af[m][kk] = *(const bf16x8*)(bufA + (row << 7) + (((kk * 4 + l4) ^ (row & 7)) << 4));
    }
#pragma unroll
    for (int n = 0; n < 4; ++n) {
      int row = hc * 128 + sb + (n & 1) * 16 + ((n >> 1) << 6) + l15;
#pragma unroll
      for (int kk = 0; kk < 2; ++kk)
        bf[n][kk] = *(const bf16x8*)(bufB + (row << 7) + (((kk * 4 + l4) ^ (row & 7)) << 4));
    }

#pragma unroll
    for (int m = 0; m < 4; ++m)
#pragma unroll
      for (int n = 0; n < 4; ++n)
#pragma unroll
        for (int kk = 0; kk < 2; ++kk)
          acc[m][n] = __builtin_amdgcn_mfma_f32_16x16x32_bf16(af[m][kk], bf[n][kk], acc[m][n], 0, 0, 0);

    if (t <= nt - 3) { asm volatile("s_waitcnt vmcnt(6)" ::: "memory"); }
    else             { asm volatile("s_waitcnt vmcnt(0)" ::: "memory"); }
    asm volatile("" ::: "memory");
    __builtin_amdgcn_s_barrier();
    asm volatile("" ::: "memory");
  }

  // ---- fused RoPE (q: bn 0..15, k: bn 16..19; v tiles skip) ----
  if (FUSE_ROPE && bn < 20) {
    float invf[2];
#pragma unroll
    for (int n = 0; n < 2; ++n) {
      int d = sb + n * 16 + l15;                 // head-local dim in [0,64)
      invf[n] = exp2f(-(float)d * 0.20762050593046007f);   // 10000^(-d/64)
    }
#pragma unroll
    for (int m = 0; m < 4; ++m)
#pragma unroll
      for (int r = 0; r < 4; ++r) {
        int row = (int)rowA0 + wr * 64 + m * 16 + l4 * 4 + r;
        float pos = (float)positions[row];
#pragma unroll
        for (int n = 0; n < 2; ++n) {
          float s, c;
          __sincosf(pos * invf[n], &s, &c);      // HW v_sin/v_cos path
          float x1 = acc[m][n][r], x2 = acc[m][n + 2][r];
          acc[m][n][r]     = x1 * c - x2 * s;
          acc[m][n + 2][r] = x2 * c + x1 * s;
        }
      }
  }

  // ---- epilogue (paired-strip col mapping) ----
#pragma unroll
  for (int m = 0; m < 4; ++m)
#pragma unroll
    for (int n = 0; n < 4; ++n)
#pragma unroll
      for (int r = 0; r < 4; ++r) {
        size_t row = rowA0 + wr * 64 + m * 16 + l4 * 4 + r;
        size_t col = rowB0 + hc * 128 + sb + (n & 1) * 16 + ((n >> 1) << 6) + l15;
        float v = acc[m][n][r];
        if (OUT_F32) ((float*)Cv)[row * Nc + col] = v;
        else         ((unsigned short*)Cv)[row * Nc + col] = f2bf(v);
      }
}

// ---------- 256x256-tile SINGLE-REGION GEMM (O-proj), 64x128 per wave ----------
template <int Kc, int Nc, int Mc, bool OUT_F32>
__global__ __launch_bounds__(512, 1) void gemmO(const unsigned short* __restrict__ A,
                                                const unsigned short* __restrict__ B,
                                                void* __restrict__ Cv) {
  __shared__ __attribute__((aligned(16))) char lds[131072];   // 2 x 64 KiB
  const int tid = threadIdx.x;
  const int wave = tid >> 6, lane = tid & 63;
  const int l15 = lane & 15, l4 = lane >> 4;
  const int wr = wave >> 1, wc = wave & 1;          // 4M x 2N grid, 64x128 each
  int bm, bn;
  xcd_decode(blockIdx.x, Mc >> 8, Nc >> 8, bm, bn);
  const size_t rowA0 = (size_t)bm << 8, rowB0 = (size_t)bn << 8;
  const int nt = Kc >> 6;

  stage_tile<4>(A, Kc, rowA0, 0, lds + 0,     tid);
  stage_tile<4>(B, Kc, rowB0, 0, lds + 32768, tid);
  asm volatile("s_waitcnt vmcnt(0)" ::: "memory");
  __builtin_amdgcn_s_barrier();

  f32x4 acc[4][8] = {};

#pragma unroll 2
  for (int t = 0; t < nt; ++t) {
    const char* cbuf = lds + (t & 1) * 65536;
    char* obuf = lds + ((t + 1) & 1) * 65536;
    const char* bufA = cbuf;
    const char* bufB = cbuf + 32768;

    if (t < nt - 1) {
      stage_tile<4>(A, Kc, rowA0, (t + 1) << 6, obuf,         tid);
      stage_tile<4>(B, Kc, rowB0, (t + 1) << 6, obuf + 32768, tid);
    }

    bf16x8 af[4][2], bf[4][2];
#pragma unroll
    for (int m = 0; m < 4; ++m) {
      int row = wr * 64 + m * 16 + l15;
#pragma unroll
      for (int kk = 0; kk < 2; ++kk)
        af[m][kk] = *(const bf16x8*)(bufA + (row << 7) + (((kk * 4 + l4) ^ (row & 7)) << 4));
    }
#pragma unroll
    for (int n = 0; n < 4; ++n) {
      int row = wc * 128 + n * 16 + l15;
#pragma unroll
      for (int kk = 0; kk < 2; ++kk)
        bf[n][kk] = *(const bf16x8*)(bufB + (row << 7) + (((kk * 4 + l4) ^ (row & 7)) << 4));
    }
#pragma unroll
    for (int m = 0; m < 4; ++m)
#pragma unroll
      for (int n = 0; n < 4; ++n)
#pragma unroll
        for (int kk = 0; kk < 2; ++kk)
          acc[m][n] = __builtin_amdgcn_mfma_f32_16x16x32_bf16(af[m][kk], bf[n][kk], acc[m][n], 0, 0, 0);
#pragma unroll
    for (int n = 0; n < 4; ++n) {
      int row = wc * 128 + (n + 4) * 16 + l15;
#pragma unroll
      for (int kk = 0; kk < 2; ++kk)
        bf[n][kk] = *(const bf16x8*)(bufB + (row << 7) + (((kk * 4 + l4) ^ (row & 7)) << 4));
    }
#pragma unroll
    for (int m = 0; m < 4; ++m)
#pragma unroll
      for (int n = 0; n < 4; ++n)
#pragma unroll
        for (int kk = 0; kk < 2; ++kk)
          acc[m][n + 4] = __builtin_amdgcn_mfma_f32_16x16x32_bf16(af[m][kk], bf[n][kk], acc[m][n + 4], 0, 0, 0);

    asm volatile("s_waitcnt vmcnt(0)" ::: "memory");
    asm volatile("" ::: "memory");
    __builtin_amdgcn_s_barrier();
    asm volatile("" ::: "memory");
  }

#pragma unroll
  for (int m = 0; m < 4; ++m)
#pragma unroll
    for (int n = 0; n < 8; ++n)
#pragma unroll
      for (int r = 0; r < 4; ++r) {
        size_t row = rowA0 + wr * 64 + m * 16 + l4 * 4 + r;
        size_t col = rowB0 + wc * 128 + n * 16 + l15;
        float v = acc[m][n][r];
        if (OUT_F32) ((float*)Cv)[row * Nc + col] = v;
        else         ((unsigned short*)Cv)[row * Nc + col] = f2bf(v);
      }
}

// ---------- flash attention (R22 proven form: setprio, unconditional rescale) ----------
__global__ __launch_bounds__(256, 4) void attn_kernel(const unsigned short* __restrict__ qkv,
                                                      unsigned short* __restrict__ ao) {
  int orig = blockIdx.x;
  int wgid = (orig & 7) * 128 + (orig >> 3);       // XCD-chunked swizzle (1024 % 8 == 0)
  int pair = wgid & 7;
  int hq = (wgid >> 3) & 31;
  int b  = wgid >> 8;
  int hk = hq >> 2;
  int tid = threadIdx.x, wave = tid >> 6, lane = tid & 63;
  int l15 = lane & 15, l4 = lane >> 4;

  __shared__ __attribute__((aligned(16))) char ldsA[16384];                 // Ks / Ps union
  __shared__ __attribute__((aligned(16))) unsigned short Vt[128][72];       // 18 KB
  unsigned short (*Ks)[128]    = (unsigned short (*)[128])ldsA;             // [64][128]
  unsigned short (*Ps)[16][72] = (unsigned short (*)[16][72])ldsA;          // [4][16][72]

  const float scale = 0.08838834764831845f;  // 1/sqrt(128)

#pragma unroll 1
  for (int iq = 0; iq < 2; ++iq) {
    const int qa = iq ? (15 - pair) : pair;        // work = qa+1 tiles; pair total = 17
    const size_t qrow0 = (size_t)(b * 1024 + qa * 64 + wave * 16);

    bf16x8 qf[4];
    {
      const unsigned short* qp = qkv + (qrow0 + l15) * 6144 + ((size_t)hq << 7) + l4 * 8;
#pragma unroll
      for (int kc = 0; kc < 4; ++kc) qf[kc] = *(const bf16x8*)(qp + kc * 32);
    }

    float m_i[4], l_i[4];
    f32x4 oacc[8];
#pragma unroll
    for (int r = 0; r < 4; ++r) { m_i[r] = -1e30f; l_i[r] = 0.0f; }
#pragma unroll
    for (int d = 0; d < 8; ++d) oacc[d] = f32x4{0.f, 0.f, 0.f, 0.f};

#pragma unroll 1
    for (int kt = 0; kt <= qa; ++kt) {
      __syncthreads();

      const unsigned short* kbase = qkv + (size_t)(b * 1024 + kt * 64) * 6144 + 4096 + ((size_t)hk << 7);
#pragma unroll
      for (int j = 0; j < 4; ++j) {
        int c = (j * 4 + wave) * 64 + lane;
        int r = c >> 4;
        int cc = (c & 15) ^ (r & 7);
        load_lds16(kbase + (size_t)r * 6144 + cc * 8, ldsA + c * 16);
      }
      {
        const unsigned short* vp = qkv + (size_t)(b * 1024 + kt * 64 + lane) * 6144 + 5120 + ((size_t)hk << 7) + wave * 32;
        u16x8 va0 = *(const u16x8*)(vp);
        u16x8 va1 = *(const u16x8*)(vp + 8);
        u16x8 va2 = *(const u16x8*)(vp + 16);
        u16x8 va3 = *(const u16x8*)(vp + 24);
        int d0 = wave * 32;
#pragma unroll
        for (int c = 0; c < 8; ++c) Vt[d0 + c][lane]      = va0[c];
#pragma unroll
        for (int c = 0; c < 8; ++c) Vt[d0 + 8 + c][lane]  = va1[c];
#pragma unroll
        for (int c = 0; c < 8; ++c) Vt[d0 + 16 + c][lane] = va2[c];
#pragma unroll
        for (int c = 0; c < 8; ++c) Vt[d0 + 24 + c][lane] = va3[c];
      }
      __syncthreads();

      float pbuf[4][4];
      float tmax[4] = {-1e30f, -1e30f, -1e30f, -1e30f};
#pragma unroll
      for (int nt = 0; nt < 4; ++nt) {
        f32x4 sacc = {0.f, 0.f, 0.f, 0.f};
        int row = nt * 16 + l15;
        __builtin_amdgcn_s_setprio(1);
#pragma unroll
        for (int kc = 0; kc < 4; ++kc) {
          const unsigned short* kp = &Ks[0][0] + row * 128 + (((kc * 4 + l4) ^ (row & 7)) * 8);
          bf16x8 kf = *(const bf16x8*)kp;
          sacc = __builtin_amdgcn_mfma_f32_16x16x32_bf16(qf[kc], kf, sacc, 0, 0, 0);
        }
        __builtin_amdgcn_s_setprio(0);
#pragma unroll
        for (int r = 0; r < 4; ++r) {
          float s = sacc[r] * scale;
          if (kt == qa) {
            int kcol = nt * 16 + l15;
            int qrow = wave * 16 + l4 * 4 + r;
            if (kcol > qrow) s = -1e30f;
          }
          pbuf[nt][r] = s;
          tmax[r] = fmaxf(tmax[r], s);
        }
      }
      __syncthreads();

#pragma unroll
      for (int r = 0; r < 4; ++r) {
        float v = tmax[r];
        v = fmaxf(v, __shfl_xor(v, 1));
        v = fmaxf(v, __shfl_xor(v, 2));
        v = fmaxf(v, __shfl_xor(v, 4));
        v = fmaxf(v, __shfl_xor(v, 8));
        tmax[r] = v;
      }
      float rescale[4];
#pragma unroll
      for (int r = 0; r < 4; ++r) {
        float mn = fmaxf(m_i[r], tmax[r]);
        rescale[r] = __expf(m_i[r] - mn);
        m_i[r] = mn;
      }
      float psum[4] = {0.f, 0.f, 0.f, 0.f};
#pragma unroll
      for (int nt = 0; nt < 4; ++nt)
#pragma unroll
        for (int r = 0; r < 4; ++r) {
          float p = __expf(pbuf[nt][r] - m_i[r]);
          pbuf[nt][r] = p;
          psum[r] += p;
        }
#pragma unroll
      for (int r = 0; r < 4; ++r) {
        float v = psum[r];
        v += __shfl_xor(v, 1);
        v += __shfl_xor(v, 2);
        v += __shfl_xor(v, 4);
        v += __shfl_xor(v, 8);
        l_i[r] = l_i[r] * rescale[r] + v;
      }
#pragma unroll
      for (int d = 0; d < 8; ++d)
#pragma unroll
        for (int r = 0; r < 4; ++r) oacc[d][r] *= rescale[r];

#pragma unroll
      for (int nt = 0; nt < 4; ++nt)
#pragma unroll
        for (int r = 0; r < 4; ++r)
          Ps[wave][l4 * 4 + r][nt * 16 + l15] = f2bf(pbuf[nt][r]);

#pragma unroll
      for (int h = 0; h < 2; ++h) {
        bf16x8 pa = *(const bf16x8*)&Ps[wave][l15][h * 32 + l4 * 8];
        __builtin_amdgcn_s_setprio(1);
#pragma unroll
        for (int d = 0; d < 8; ++d) {
          bf16x8 vf = *(const bf16x8*)&Vt[d * 16 + l15][h * 32 + l4 * 8];
          oacc[d] = __builtin_amdgcn_mfma_f32_16x16x32_bf16(pa, vf, oacc[d], 0, 0, 0);
        }
        __builtin_amdgcn_s_setprio(0);
      }
    }

#pragma unroll
    for (int d = 0; d < 8; ++d)
#pragma unroll
      for (int r = 0; r < 4; ++r) {
        size_t row = qrow0 + l4 * 4 + r;
        size_t col = ((size_t)hq << 7) + d * 16 + l15;
        ao[row * 4096 + col] = f2bf(oacc[d][r] / l_i[r]);
      }
  }
}

// ---------- launch ----------
extern "C" void kernel_launch(void* const* d_in, const int* in_sizes, int n_in,
                              void* d_out, int out_size, void* d_ws, size_t ws_size,
                              hipStream_t stream) {
  const float* hidden    = (const float*)d_in[0];
  const int*   positions = (const int*)d_in[1];
  const float* q_w       = (const float*)d_in[2];
  const float* k_w       = (const float*)d_in[3];
  const float* v_w       = (const float*)d_in[4];
  const float* o_w       = (const float*)d_in[5];
  float* out = (float*)d_out;

  char* ws = (char*)d_ws;
  unsigned short* hidB  = (unsigned short*)(ws);                 // 32 MB  [4096,4096]
  unsigned short* wqkvB = (unsigned short*)(ws + 33554432);      // 48 MB  [6144,4096]
  unsigned short* woB   = (unsigned short*)(ws + 83886080);      // 32 MB  [4096,4096]
  unsigned short* qkvB  = (unsigned short*)(ws + 117440512);     // 48 MB  [4096,6144]
  unsigned short* aoB   = (unsigned short*)(ws + 167772160);     // 32 MB  [4096,4096]

  // f32 -> bf16 (all 5 tensors, one dispatch: 14680064 float4 / 256 = 57344 blocks)
  cvt_all<<<57344, 256, 0, stream>>>(hidden, q_w, k_w, v_w, o_w, hidB, wqkvB, woB);

  // fused QKV projection + RoPE: [4096,6144] = hid @ wqkv^T (768 tiles, 3 exact waves)
  gemmP<4096, 6144, 4096, false, true><<<768, 512, 0, stream>>>(hidB, wqkvB, (void*)qkvB, positions);

  // causal GQA flash attention (QBLK=64 + setprio, unconditional rescale)
  attn_kernel<<<1024, 256, 0, stream>>>(qkvB, aoB);

  // output projection: [4096,4096] = ao @ o_w^T (256 tiles, 1 exact wave, f32 out)
  gemmO<4096, 4096, 4096, true><<<256, 512, 0, stream>>>(aoB, woB, (void*)out);
}